// Round 10
// baseline (207.386 us; speedup 1.0000x reference)
//
#include <hip/hip_runtime.h>
#include <math.h>

// ---------------------------------------------------------------------------
// Mamba3DBlock forward. B=4, Npts=2048, C=384, K_GROUP=8. x rows = 8196.
// R10: cv via 192-way k-split partials (+1-block reduce); GEMM depth-2
//      prefetch (K-loop unrolled x2, two named reg sets, loads 2 tiles ahead).
// ---------------------------------------------------------------------------

#define C384 384

typedef __attribute__((ext_vector_type(8))) short short8;
typedef __attribute__((ext_vector_type(4))) float f32x4;

__device__ __forceinline__ float gelu_exact(float v) {
    return 0.5f * v * (1.0f + erff(v * 0.7071067811865475f));
}

__device__ __forceinline__ unsigned short f2bf(float f) {
    unsigned u = __float_as_uint(f);
    u += 0x7fffu + ((u >> 16) & 1u);
    return (unsigned short)(u >> 16);
}

// ---------------- LayerNorm: one wave per row, no barriers ------------------
template <bool OUTBF>
__global__ __launch_bounds__(256) void ln_kernel(const float* __restrict__ in,
                                                 void* __restrict__ outp,
                                                 const float* __restrict__ gw,
                                                 const float* __restrict__ bw) {
    int w = threadIdx.x >> 6, l = threadIdx.x & 63;
    int row = blockIdx.x * 4 + w;
    const float* x = in + (size_t)row * C384;
    float v[6];
    float s = 0.f;
#pragma unroll
    for (int i = 0; i < 6; ++i) { v[i] = x[l + 64 * i]; s += v[i]; }
#pragma unroll
    for (int off = 32; off; off >>= 1) s += __shfl_xor(s, off, 64);
    float m = s * (1.0f / 384.0f);
    float s2 = 0.f;
#pragma unroll
    for (int i = 0; i < 6; ++i) { v[i] -= m; s2 += v[i] * v[i]; }
#pragma unroll
    for (int off = 32; off; off >>= 1) s2 += __shfl_xor(s2, off, 64);
    float rstd = 1.0f / sqrtf(s2 * (1.0f / 384.0f) + 1e-5f);
#pragma unroll
    for (int i = 0; i < 6; ++i) {
        int c = l + 64 * i;
        float o = v[i] * rstd * gw[c] + bw[c];
        if (OUTBF) ((unsigned short*)outp)[(size_t)row * C384 + c] = f2bf(o);
        else       ((float*)outp)[(size_t)row * C384 + c] = o;
    }
}

// ---------------- prep: transposes + pts4 + cv partials (k-split) -----------
__global__ __launch_bounds__(256) void prep_kernel(const float* __restrict__ w2,
                                                   const float* __restrict__ m1,
                                                   const float* __restrict__ m2,
                                                   const float* __restrict__ center,
                                                   const float* __restrict__ beta,
                                                   const float* __restrict__ w1,
                                                   unsigned short* __restrict__ o2,
                                                   unsigned short* __restrict__ o3,
                                                   unsigned short* __restrict__ o4,
                                                   float4* __restrict__ pts,
                                                   float* __restrict__ cvpart) {
    int tid = blockIdx.x;
    if (tid < 1296) {
        const float* in; unsigned short* outp; int K, N, local;
        if (tid < 144)      { in = w2; outp = o2; K = 384;  N = 384;  local = tid; }
        else if (tid < 720) { in = m1; outp = o3; K = 384;  N = 1536; local = tid - 144; }
        else                { in = m2; outp = o4; K = 1536; N = 384;  local = tid - 720; }
        int ntN = N >> 5;
        int kb = (local / ntN) * 32, nb = (local % ntN) * 32;
        __shared__ float tile[32][33];
        int c = threadIdx.x & 31, r0 = threadIdx.x >> 5;
#pragma unroll
        for (int i = 0; i < 4; ++i) {
            int r = r0 + i * 8;
            tile[r][c] = in[(size_t)(kb + r) * N + nb + c];
        }
        __syncthreads();
#pragma unroll
        for (int i = 0; i < 4; ++i) {
            int r = r0 + i * 8;
            outp[(size_t)(nb + r) * K + kb + c] = f2bf(tile[c][r]);
        }
    } else if (tid < 1328) {
        int p = (tid - 1296) * 256 + threadIdx.x;    // 0..8191
        float cx = center[p * 3], cy = center[p * 3 + 1], cz = center[p * 3 + 2];
        float sq = cx * cx + cy * cy + cz * cz;
        pts[p] = make_float4(cx, cy, cz, sq);
    } else {
        // cv partials: 192 blocks = 32 k-splits x 6 n-blocks, 24 k each
        int local = tid - 1328;                      // 0..191
        int nblk = local % 6, ks = local / 6;
        if (threadIdx.x < 64) {
            int n = nblk * 64 + threadIdx.x;
            float s = 0.f;
            int k0 = ks * 24;
#pragma unroll
            for (int j = 0; j < 24; ++j)
                s = fmaf(beta[k0 + j], w1[(size_t)(k0 + j) * 384 + n], s);
            cvpart[(size_t)ks * 384 + n] = s;
        }
    }
}

// ---------------- cv reduce: cv[n] = b1[n] + sum_ks cvpart[ks][n] -----------
__global__ __launch_bounds__(384) void cvreduce_kernel(const float* __restrict__ cvpart,
                                                       const float* __restrict__ b1,
                                                       float* __restrict__ cv) {
    int n = threadIdx.x;
    float s = b1[n];
#pragma unroll
    for (int ks = 0; ks < 32; ++ks) s += cvpart[(size_t)ks * 384 + n];
    cv[n] = s;
}

// ---------------- W1 transpose+cast with inv folded into top K-half ---------
__global__ __launch_bounds__(256) void tcastw1_kernel(const float* __restrict__ w1,
                                                      const float* __restrict__ stdbuf,
                                                      unsigned short* __restrict__ o1) {
    int tid = blockIdx.x;                    // 288 tiles: K=768 x N=384
    int kb = (tid / 12) * 32, nb = (tid % 12) * 32;
    float scale = (kb < 384) ? stdbuf[0] : 1.0f;
    __shared__ float tile[32][33];
    int c = threadIdx.x & 31, r0 = threadIdx.x >> 5;
#pragma unroll
    for (int i = 0; i < 4; ++i) {
        int r = r0 + i * 8;
        tile[r][c] = w1[(size_t)(kb + r) * 384 + nb + c];
    }
    __syncthreads();
#pragma unroll
    for (int i = 0; i < 4; ++i) {
        int r = r0 + i * 8;
        o1[(size_t)(nb + r) * 768 + kb + c] = f2bf(tile[c][r] * scale);
    }
}

// ---------------- KNN: one wave per query, pts4 + group-min cache -----------
__global__ __launch_bounds__(256) void knn_kernel(const float4* __restrict__ pts,
                                                  int* __restrict__ idx_out) {
    int w = threadIdx.x >> 6;
    int l = threadIdx.x & 63;
    int q = blockIdx.x * 4 + w;
    int b = q >> 11, n = q & 2047;
    const float4* pb = pts + (size_t)b * 2048;
    float4 qp = pb[n];
    float sqq = qp.w;
    unsigned val[32];
    unsigned long long gv[8];
#pragma unroll
    for (int g = 0; g < 8; ++g) {
        unsigned long long kmin = ~0ULL;
#pragma unroll
        for (int j = 0; j < 4; ++j) {
            int i = g * 4 + j;
            float4 c = pb[i * 64 + l];
            float dot = qp.x * c.x + qp.y * c.y + qp.z * c.z;
            float d2 = (sqq + c.w) - 2.0f * dot;
            unsigned u = __float_as_uint(d2);
            u ^= (unsigned)(((int)u >> 31) | 0x80000000);
            val[i] = u;
            unsigned long long kk = ((unsigned long long)u << 32) | (unsigned)i;
            kmin = kk < kmin ? kk : kmin;
        }
        gv[g] = kmin;
    }
    unsigned long long lm = gv[0];
#pragma unroll
    for (int g = 1; g < 8; ++g) lm = gv[g] < lm ? gv[g] : lm;

    for (int sel = 0; sel < 8; ++sel) {
        unsigned wval = (unsigned)(lm >> 32);
        unsigned wmin = wval;
#pragma unroll
        for (int off = 32; off; off >>= 1) {
            unsigned o = (unsigned)__shfl_xor((int)wmin, off, 64);
            wmin = o < wmin ? o : wmin;
        }
        bool eligible = (wval == wmin);
        unsigned long long mask = __ballot(eligible);
        unsigned myM = ((unsigned)lm) * 64u + (unsigned)l;
        if (__popcll(mask) > 1) {
            unsigned mc = eligible ? myM : 0xFFFFFFFFu;
#pragma unroll
            for (int off = 32; off; off >>= 1) {
                unsigned o = (unsigned)__shfl_xor((int)mc, off, 64);
                mc = o < mc ? o : mc;
            }
            eligible = eligible && (myM == mc);
        }
        if (eligible) {
            idx_out[(size_t)q * 8 + sel] = (int)myM;
            unsigned ws = (unsigned)lm;
#pragma unroll
            for (int g = 0; g < 8; ++g) {
                if (gv[g] == lm) {
                    asm volatile("" ::: "memory");
                    unsigned long long kmin = ~0ULL;
#pragma unroll
                    for (int j = 0; j < 4; ++j) {
                        int i = g * 4 + j;
                        unsigned v = ((unsigned)i == ws) ? 0xFFFFFFFFu : val[i];
                        val[i] = v;
                        unsigned long long kk = ((unsigned long long)v << 32) | (unsigned)i;
                        kmin = kk < kmin ? kk : kmin;
                    }
                    gv[g] = kmin;
                }
            }
            unsigned long long nlm = gv[0];
#pragma unroll
            for (int g = 1; g < 8; ++g) nlm = gv[g] < nlm ? gv[g] : nlm;
            lm = nlm;
        }
    }
}

// ---------------- gather: sums + std partials + ef' (bf16) fused ------------
__global__ __launch_bounds__(128) void gather_kernel(const float* __restrict__ xn,
                                                     const int* __restrict__ idxb,
                                                     const float* __restrict__ alpha,
                                                     unsigned short* __restrict__ efp,
                                                     float2* __restrict__ part) {
    int q = blockIdx.x;
    int b = q >> 11;
    int t = threadIdx.x;
    __shared__ int sidx[8];
    if (t < 8) sidx[t] = idxb[(size_t)q * 8 + t];
    __syncthreads();
    const float* xno = xn + ((size_t)b * 2049 + 1) * C384;
    const float* xc  = xn + ((size_t)q + b + 1) * C384;
    float s1 = 0.f, s2 = 0.f;
    for (int c = t; c < C384; c += 128) {
        float xcv = xc[c];
        float acc = 0.f;
#pragma unroll
        for (int k = 0; k < 8; ++k) {
            float v = xno[(size_t)sidx[k] * C384 + c];
            acc += v;
            float d = v - xcv;
            s1 += d;
            s2 += d * d;
        }
        float mk = acc * 0.125f;
        efp[(size_t)q * 768 + c]       = f2bf(alpha[c] * (mk - xcv));
        efp[(size_t)q * 768 + 384 + c] = f2bf(alpha[384 + c] * xcv);
    }
    __shared__ float r1[128], r2[128];
    r1[t] = s1; r2[t] = s2;
    __syncthreads();
#pragma unroll
    for (int s = 64; s; s >>= 1) {
        if (t < s) { r1[t] += r1[t + s]; r2[t] += r2[t + s]; }
        __syncthreads();
    }
    if (t == 0) part[q] = make_float2(r1[0], r2[0]);
}

// ---------------- reduce std partials -> inv = 1/(std+1e-5) -----------------
__global__ __launch_bounds__(256) void std_kernel(const float2* __restrict__ part,
                                                  float* __restrict__ stdbuf) {
    int t = threadIdx.x;
    double s1 = 0.0, s2 = 0.0;
    for (int i = t; i < 8192; i += 256) {
        float2 p = part[i];
        s1 += (double)p.x;
        s2 += (double)p.y;
    }
    __shared__ double r1[256], r2[256];
    r1[t] = s1; r2[t] = s2;
    __syncthreads();
#pragma unroll
    for (int s = 128; s; s >>= 1) {
        if (t < s) { r1[t] += r1[t + s]; r2[t] += r2[t + s]; }
        __syncthreads();
    }
    if (t == 0) {
        const double N = 25165824.0;
        double var = (r2[0] - r1[0] * r1[0] / N) / (N - 1.0);
        float stdf = (float)sqrt(var);
        stdbuf[0] = 1.0f / (stdf + 1e-5f);
    }
}

// ---------------- cls rows ----------------------------------------------------
__global__ void cls_kernel(const float* __restrict__ x,
                           const float* __restrict__ xn,
                           float* __restrict__ out) {
    int b = blockIdx.x;
    int c = threadIdx.x;
    size_t r = (size_t)b * 2049 * C384 + c;
    out[r] = x[r] + xn[r];
}

// ---------------- bf16 MFMA GEMM, 64x64 tile, BK=64, depth-2 prefetch --------
// (R6 config + loads issued 2 K-tiles ahead; K-loop unrolled x2, nt even.)
#define ST_STR 68

template <bool GELU, bool REMAP, bool RES, bool OUTBF>
__global__ __launch_bounds__(256) void mfma_gemm(const unsigned short* __restrict__ A,
                                                 const unsigned short* __restrict__ Bt,
                                                 const float* __restrict__ bias,
                                                 const float* __restrict__ res,
                                                 void* __restrict__ outp,
                                                 int M, int N, int K, int ntn) {
    __shared__ char smem[32768];
    int t = threadIdx.x;
    int lane = t & 63, w = t >> 6;
    int wr = w >> 1, wc = w & 1;

    int nwg = gridDim.x;
    int q8 = nwg >> 3, r8 = nwg & 7;
    int xcd = blockIdx.x & 7, idx = blockIdx.x >> 3;
    int lid = (xcd < r8 ? xcd * (q8 + 1) : r8 * (q8 + 1) + (xcd - r8) * q8) + idx;
    int by = lid / ntn, bx = lid - by * ntn;
    int bm = by * 64, bn = bx * 64;

    f32x4 acc[2][2] = {};

    int srow = t >> 3;
    int sc16 = t & 7;
    int swz = (sc16 ^ (srow & 7)) << 4;

    const unsigned short* pa0 = A + (size_t)(bm + srow) * K + sc16 * 8;
    const unsigned short* pa1 = A + (size_t)(bm + srow + 32) * K + sc16 * 8;
    const unsigned short* pb0 = Bt + (size_t)(bn + srow) * K + sc16 * 8;
    const unsigned short* pb1 = Bt + (size_t)(bn + srow + 32) * K + sc16 * 8;
    bool ok0 = (bm + srow) < M, ok1 = (bm + srow + 32) < M;
    const uint4 zz = make_uint4(0u, 0u, 0u, 0u);

    auto stage = [&](char* dst, uint4 va0, uint4 va1, uint4 vb0, uint4 vb1) {
        *(uint4*)(dst + srow * 128 + swz) = va0;
        *(uint4*)(dst + (srow + 32) * 128 + swz) = va1;
        char* dB = dst + 8192;
        *(uint4*)(dB + srow * 128 + swz) = vb0;
        *(uint4*)(dB + (srow + 32) * 128 + swz) = vb1;
    };
    auto compute = [&](const char* smA) {
        const char* smB = smA + 8192;
#pragma unroll
        for (int ks = 0; ks < 2; ++ks) {
            short8 af[2], bfr[2];
            int cb = ks * 4 + (lane >> 4);
#pragma unroll
            for (int mi = 0; mi < 2; ++mi) {
                int row = wr * 32 + mi * 16 + (lane & 15);
                af[mi] = *(const short8*)(smA + row * 128 + ((cb ^ (row & 7)) << 4));
            }
#pragma unroll
            for (int nj = 0; nj < 2; ++nj) {
                int row = wc * 32 + nj * 16 + (lane & 15);
                bfr[nj] = *(const short8*)(smB + row * 128 + ((cb ^ (row & 7)) << 4));
            }
#pragma unroll
            for (int mi = 0; mi < 2; ++mi)
#pragma unroll
                for (int nj = 0; nj < 2; ++nj)
                    acc[mi][nj] = __builtin_amdgcn_mfma_f32_16x16x32_bf16(
                        af[mi], bfr[nj], acc[mi][nj], 0, 0, 0);
        }
    };

    // prologue: tile 0 -> set a -> buf0; tile 1 -> set b (in flight)
    uint4 A0a = ok0 ? *(const uint4*)pa0 : zz;
    uint4 A1a = ok1 ? *(const uint4*)pa1 : zz;
    uint4 B0a = *(const uint4*)pb0;
    uint4 B1a = *(const uint4*)pb1;
    stage(smem, A0a, A1a, B0a, B1a);
    uint4 A0b = ok0 ? *(const uint4*)(pa0 + 64) : zz;
    uint4 A1b = ok1 ? *(const uint4*)(pa1 + 64) : zz;
    uint4 B0b = *(const uint4*)(pb0 + 64);
    uint4 B1b = *(const uint4*)(pb1 + 64);

    int nt = K >> 6;                       // even for all our K
    for (int tix = 0; tix < nt; tix += 2) {
        bool h2 = (tix + 2) < nt, h3 = (tix + 3) < nt;
        if (h2) {                          // issue tile t+2 -> set a
            int ko = (tix + 2) << 6;
            A0a = ok0 ? *(const uint4*)(pa0 + ko) : zz;
            A1a = ok1 ? *(const uint4*)(pa1 + ko) : zz;
            B0a = *(const uint4*)(pb0 + ko);
            B1a = *(const uint4*)(pb1 + ko);
        }
        __syncthreads();                   // buf0 = tile t ready
        compute(smem);
        stage(smem + 16384, A0b, A1b, B0b, B1b);   // tile t+1 -> buf1
        if (h3) {                          // issue tile t+3 -> set b
            int ko = (tix + 3) << 6;
            A0b = ok0 ? *(const uint4*)(pa0 + ko) : zz;
            A1b = ok1 ? *(const uint4*)(pa1 + ko) : zz;
            B0b = *(const uint4*)(pb0 + ko);
            B1b = *(const uint4*)(pb1 + ko);
        }
        __syncthreads();                   // buf1 = tile t+1 ready
        compute(smem + 16384);
        if (h2) stage(smem, A0a, A1a, B0a, B1a);   // tile t+2 -> buf0
    }

    // ---- epilogue: stage f32 tile in LDS, then coalesced full-line stores ----
    __syncthreads();
    float* st = (float*)smem;
#pragma unroll
    for (int nj = 0; nj < 2; ++nj) {
        int nl = wc * 32 + nj * 16 + (lane & 15);
        float bs = bias[bn + nl];
#pragma unroll
        for (int mi = 0; mi < 2; ++mi) {
#pragma unroll
            for (int r = 0; r < 4; ++r) {
                int ml = wr * 32 + mi * 16 + (lane >> 4) * 4 + r;
                float v = acc[mi][nj][r] + bs;
                if (GELU) v = gelu_exact(v);
                st[ml * ST_STR + nl] = v;
            }
        }
    }
    __syncthreads();
    if (OUTBF) {
#pragma unroll
        for (int i = 0; i < 2; ++i) {
            int chunk = t + i * 256;
            int ml = chunk >> 3, c8 = (chunk & 7) * 8;
            int m = bm + ml;
            if (m < M) {
                unsigned short tmp[8];
#pragma unroll
                for (int j = 0; j < 8; ++j) tmp[j] = f2bf(st[ml * ST_STR + c8 + j]);
                *(uint4*)((unsigned short*)outp + (size_t)m * N + bn + c8) = *(uint4*)tmp;
            }
        }
    } else {
#pragma unroll
        for (int i = 0; i < 4; ++i) {
            int chunk = t + i * 256;
            int ml = chunk >> 4, c4 = (chunk & 15) * 4;
            int m = bm + ml;
            if (m < M) {
                size_t orow = REMAP ? (size_t)(m + (m >> 11) + 1) : (size_t)m;
                size_t off = orow * (size_t)N + bn + c4;
                float4 v = *(float4*)&st[ml * ST_STR + c4];
                if (RES) {
                    float4 rv = *(const float4*)(res + off);
                    v.x += rv.x; v.y += rv.y; v.z += rv.z; v.w += rv.w;
                }
                *(float4*)((float*)outp + off) = v;
            }
        }
    }
}

// ---------------------------------------------------------------------------
extern "C" void kernel_launch(void* const* d_in, const int* in_sizes, int n_in,
                              void* d_out, int out_size, void* d_ws, size_t ws_size,
                              hipStream_t stream) {
    const float* center  = (const float*)d_in[0];
    const float* x       = (const float*)d_in[1];
    const float* ln1_g   = (const float*)d_in[2];
    const float* ln1_b   = (const float*)d_in[3];
    const float* alpha   = (const float*)d_in[4];
    const float* beta    = (const float*)d_in[5];
    const float* attn_w1 = (const float*)d_in[6];
    const float* attn_b1 = (const float*)d_in[7];
    const float* attn_w2 = (const float*)d_in[8];
    const float* attn_b2 = (const float*)d_in[9];
    const float* ln2_g   = (const float*)d_in[10];
    const float* ln2_b   = (const float*)d_in[11];
    const float* mlp_w1  = (const float*)d_in[12];
    const float* mlp_b1  = (const float*)d_in[13];
    const float* mlp_w2  = (const float*)d_in[14];
    const float* mlp_b2  = (const float*)d_in[15];
    float* out = (float*)d_out;

    // workspace layout (bytes; g overlays dead xn/efp region)
    char* wsb = (char*)d_ws;
    float*          xn     = (float*)(wsb + 0);                  // 12,589,056 (ln1->cls)
    unsigned short* efp    = (unsigned short*)(wsb + 12589056);  // 12,582,912 (gather->gemm1)
    int*            idxb   = (int*)(wsb + 25171968);             // 262,144
    float2*         part   = (float2*)(wsb + 25434112);          // 65,536
    float*          stdbuf = (float*)(wsb + 25499648);           // 256
    float4*         pts4   = (float4*)(wsb + 25499904);          // 131,072
    float*          cv     = (float*)(wsb + 25630976);           // 1,536
    unsigned short* h1     = (unsigned short*)(wsb + 25632512);  // 6,291,456 (gemm1->gemm2)
    unsigned short* yb     = (unsigned short*)(wsb + 31923968);  // 6,294,528 (ln2->gemm3)
    unsigned short* g      = (unsigned short*)(wsb + 0);         // 25,178,112 overlay (gemm3->gemm4)
    unsigned short* w1T    = (unsigned short*)(wsb + 38218496);  // 589,824
    unsigned short* w2T    = (unsigned short*)(wsb + 38808320);  // 294,912
    unsigned short* mw1T   = (unsigned short*)(wsb + 39103232);  // 1,179,648
    unsigned short* mw2T   = (unsigned short*)(wsb + 40282880);  // 1,179,648 -> 41,462,528
    float*          cvpart = (float*)(wsb + 41462528);           // 32*384*4 = 49,152

    // 0. prep: transposes + pts4 + cv partials
    prep_kernel<<<1520, 256, 0, stream>>>(attn_w2, mlp_w1, mlp_w2, center, beta,
                                          attn_w1, w2T, mw1T, mw2T, pts4, cvpart);
    // 0b. cv reduce
    cvreduce_kernel<<<1, 384, 0, stream>>>(cvpart, attn_b1, cv);
    // 1. LN1 (f32)
    ln_kernel<false><<<2049, 256, 0, stream>>>(x, xn, ln1_g, ln1_b);
    // 2. KNN
    knn_kernel<<<2048, 256, 0, stream>>>(pts4, idxb);
    // 3. gather (+fused ef')
    gather_kernel<<<8192, 128, 0, stream>>>(xn, idxb, alpha, efp, part);
    // 4. std -> inv
    std_kernel<<<1, 256, 0, stream>>>(part, stdbuf);
    // 5. W1 transpose+cast with inv on top half
    tcastw1_kernel<<<288, 256, 0, stream>>>(attn_w1, stdbuf, w1T);
    // 6. h1 = gelu(ef' @ w1T + cv)       M=8192 N=384 K=768  (128 x 6)
    mfma_gemm<true, false, false, true><<<768, 256, 0, stream>>>(
        efp, w1T, cv, nullptr, h1, 8192, 384, 768, 6);
    // 7. out[remap] = x + h1 @ w2T + b2  M=8192 N=384 K=384
    mfma_gemm<false, true, true, false><<<768, 256, 0, stream>>>(
        h1, w2T, attn_b2, x, out, 8192, 384, 384, 6);
    // 7b. cls rows
    cls_kernel<<<4, 384, 0, stream>>>(x, xn, out);
    // 8. LN2 -> yb bf16
    ln_kernel<true><<<2049, 256, 0, stream>>>(out, yb, ln2_g, ln2_b);
    // 9. g = gelu(yb @ mw1T + b1)        M=8196 N=1536 K=384  (129 x 24)
    mfma_gemm<true, false, false, true><<<3096, 256, 0, stream>>>(
        yb, mw1T, mlp_b1, nullptr, g, 8196, 1536, 384, 24);
    // 10. out += g @ mw2T + b2           M=8196 N=384 K=1536  (129 x 6)
    mfma_gemm<false, false, true, false><<<774, 256, 0, stream>>>(
        g, mw2T, mlp_b2, out, out, 8196, 384, 1536, 6);
}

// Round 11
// 148.695 us; speedup vs baseline: 1.3947x; 1.3947x over previous
//
#include <hip/hip_runtime.h>
#include <math.h>

// ---------------------------------------------------------------------------
// Mamba3DBlock forward. B=4, Npts=2048, C=384, K_GROUP=8. x rows = 8196.
// R11: single-depth GEMM (R6 schedule) with raw s_barrier + lgkmcnt-only wait
//      (loads stay in flight across barrier); cv via k-split partials (R10).
// ---------------------------------------------------------------------------

#define C384 384

typedef __attribute__((ext_vector_type(8))) short short8;
typedef __attribute__((ext_vector_type(4))) float f32x4;

__device__ __forceinline__ float gelu_exact(float v) {
    return 0.5f * v * (1.0f + erff(v * 0.7071067811865475f));
}

__device__ __forceinline__ unsigned short f2bf(float f) {
    unsigned u = __float_as_uint(f);
    u += 0x7fffu + ((u >> 16) & 1u);
    return (unsigned short)(u >> 16);
}

// lgkmcnt(0) + collective barrier; loads (vmcnt) stay in flight.
__device__ __forceinline__ void lds_barrier() {
    asm volatile("s_waitcnt lgkmcnt(0)" ::: "memory");
    __builtin_amdgcn_s_barrier();
    asm volatile("" ::: "memory");
}

// ---------------- LayerNorm: one wave per row, no barriers ------------------
template <bool OUTBF>
__global__ __launch_bounds__(256) void ln_kernel(const float* __restrict__ in,
                                                 void* __restrict__ outp,
                                                 const float* __restrict__ gw,
                                                 const float* __restrict__ bw) {
    int w = threadIdx.x >> 6, l = threadIdx.x & 63;
    int row = blockIdx.x * 4 + w;
    const float* x = in + (size_t)row * C384;
    float v[6];
    float s = 0.f;
#pragma unroll
    for (int i = 0; i < 6; ++i) { v[i] = x[l + 64 * i]; s += v[i]; }
#pragma unroll
    for (int off = 32; off; off >>= 1) s += __shfl_xor(s, off, 64);
    float m = s * (1.0f / 384.0f);
    float s2 = 0.f;
#pragma unroll
    for (int i = 0; i < 6; ++i) { v[i] -= m; s2 += v[i] * v[i]; }
#pragma unroll
    for (int off = 32; off; off >>= 1) s2 += __shfl_xor(s2, off, 64);
    float rstd = 1.0f / sqrtf(s2 * (1.0f / 384.0f) + 1e-5f);
#pragma unroll
    for (int i = 0; i < 6; ++i) {
        int c = l + 64 * i;
        float o = v[i] * rstd * gw[c] + bw[c];
        if (OUTBF) ((unsigned short*)outp)[(size_t)row * C384 + c] = f2bf(o);
        else       ((float*)outp)[(size_t)row * C384 + c] = o;
    }
}

// ---------------- prep: transposes + pts4 + cv partials (k-split) -----------
__global__ __launch_bounds__(256) void prep_kernel(const float* __restrict__ w2,
                                                   const float* __restrict__ m1,
                                                   const float* __restrict__ m2,
                                                   const float* __restrict__ center,
                                                   const float* __restrict__ beta,
                                                   const float* __restrict__ w1,
                                                   unsigned short* __restrict__ o2,
                                                   unsigned short* __restrict__ o3,
                                                   unsigned short* __restrict__ o4,
                                                   float4* __restrict__ pts,
                                                   float* __restrict__ cvpart) {
    int tid = blockIdx.x;
    if (tid < 1296) {
        const float* in; unsigned short* outp; int K, N, local;
        if (tid < 144)      { in = w2; outp = o2; K = 384;  N = 384;  local = tid; }
        else if (tid < 720) { in = m1; outp = o3; K = 384;  N = 1536; local = tid - 144; }
        else                { in = m2; outp = o4; K = 1536; N = 384;  local = tid - 720; }
        int ntN = N >> 5;
        int kb = (local / ntN) * 32, nb = (local % ntN) * 32;
        __shared__ float tile[32][33];
        int c = threadIdx.x & 31, r0 = threadIdx.x >> 5;
#pragma unroll
        for (int i = 0; i < 4; ++i) {
            int r = r0 + i * 8;
            tile[r][c] = in[(size_t)(kb + r) * N + nb + c];
        }
        __syncthreads();
#pragma unroll
        for (int i = 0; i < 4; ++i) {
            int r = r0 + i * 8;
            outp[(size_t)(nb + r) * K + kb + c] = f2bf(tile[c][r]);
        }
    } else if (tid < 1328) {
        int p = (tid - 1296) * 256 + threadIdx.x;    // 0..8191
        float cx = center[p * 3], cy = center[p * 3 + 1], cz = center[p * 3 + 2];
        float sq = cx * cx + cy * cy + cz * cz;
        pts[p] = make_float4(cx, cy, cz, sq);
    } else {
        // cv partials: 192 blocks = 32 k-splits x 6 n-blocks, 24 k each
        int local = tid - 1328;                      // 0..191
        int nblk = local % 6, ks = local / 6;
        if (threadIdx.x < 64) {
            int n = nblk * 64 + threadIdx.x;
            float s = 0.f;
            int k0 = ks * 24;
#pragma unroll
            for (int j = 0; j < 24; ++j)
                s = fmaf(beta[k0 + j], w1[(size_t)(k0 + j) * 384 + n], s);
            cvpart[(size_t)ks * 384 + n] = s;
        }
    }
}

// ---------------- cv reduce: cv[n] = b1[n] + sum_ks cvpart[ks][n] -----------
__global__ __launch_bounds__(384) void cvreduce_kernel(const float* __restrict__ cvpart,
                                                       const float* __restrict__ b1,
                                                       float* __restrict__ cv) {
    int n = threadIdx.x;
    float s = b1[n];
#pragma unroll
    for (int ks = 0; ks < 32; ++ks) s += cvpart[(size_t)ks * 384 + n];
    cv[n] = s;
}

// ---------------- W1 transpose+cast with inv folded into top K-half ---------
__global__ __launch_bounds__(256) void tcastw1_kernel(const float* __restrict__ w1,
                                                      const float* __restrict__ stdbuf,
                                                      unsigned short* __restrict__ o1) {
    int tid = blockIdx.x;                    // 288 tiles: K=768 x N=384
    int kb = (tid / 12) * 32, nb = (tid % 12) * 32;
    float scale = (kb < 384) ? stdbuf[0] : 1.0f;
    __shared__ float tile[32][33];
    int c = threadIdx.x & 31, r0 = threadIdx.x >> 5;
#pragma unroll
    for (int i = 0; i < 4; ++i) {
        int r = r0 + i * 8;
        tile[r][c] = w1[(size_t)(kb + r) * 384 + nb + c];
    }
    __syncthreads();
#pragma unroll
    for (int i = 0; i < 4; ++i) {
        int r = r0 + i * 8;
        o1[(size_t)(nb + r) * 768 + kb + c] = f2bf(tile[c][r] * scale);
    }
}

// ---------------- KNN: one wave per query, pts4 + group-min cache -----------
__global__ __launch_bounds__(256) void knn_kernel(const float4* __restrict__ pts,
                                                  int* __restrict__ idx_out) {
    int w = threadIdx.x >> 6;
    int l = threadIdx.x & 63;
    int q = blockIdx.x * 4 + w;
    int b = q >> 11, n = q & 2047;
    const float4* pb = pts + (size_t)b * 2048;
    float4 qp = pb[n];
    float sqq = qp.w;
    unsigned val[32];
    unsigned long long gv[8];
#pragma unroll
    for (int g = 0; g < 8; ++g) {
        unsigned long long kmin = ~0ULL;
#pragma unroll
        for (int j = 0; j < 4; ++j) {
            int i = g * 4 + j;
            float4 c = pb[i * 64 + l];
            float dot = qp.x * c.x + qp.y * c.y + qp.z * c.z;
            float d2 = (sqq + c.w) - 2.0f * dot;
            unsigned u = __float_as_uint(d2);
            u ^= (unsigned)(((int)u >> 31) | 0x80000000);
            val[i] = u;
            unsigned long long kk = ((unsigned long long)u << 32) | (unsigned)i;
            kmin = kk < kmin ? kk : kmin;
        }
        gv[g] = kmin;
    }
    unsigned long long lm = gv[0];
#pragma unroll
    for (int g = 1; g < 8; ++g) lm = gv[g] < lm ? gv[g] : lm;

    for (int sel = 0; sel < 8; ++sel) {
        unsigned wval = (unsigned)(lm >> 32);
        unsigned wmin = wval;
#pragma unroll
        for (int off = 32; off; off >>= 1) {
            unsigned o = (unsigned)__shfl_xor((int)wmin, off, 64);
            wmin = o < wmin ? o : wmin;
        }
        bool eligible = (wval == wmin);
        unsigned long long mask = __ballot(eligible);
        unsigned myM = ((unsigned)lm) * 64u + (unsigned)l;
        if (__popcll(mask) > 1) {
            unsigned mc = eligible ? myM : 0xFFFFFFFFu;
#pragma unroll
            for (int off = 32; off; off >>= 1) {
                unsigned o = (unsigned)__shfl_xor((int)mc, off, 64);
                mc = o < mc ? o : mc;
            }
            eligible = eligible && (myM == mc);
        }
        if (eligible) {
            idx_out[(size_t)q * 8 + sel] = (int)myM;
            unsigned ws = (unsigned)lm;
#pragma unroll
            for (int g = 0; g < 8; ++g) {
                if (gv[g] == lm) {
                    asm volatile("" ::: "memory");
                    unsigned long long kmin = ~0ULL;
#pragma unroll
                    for (int j = 0; j < 4; ++j) {
                        int i = g * 4 + j;
                        unsigned v = ((unsigned)i == ws) ? 0xFFFFFFFFu : val[i];
                        val[i] = v;
                        unsigned long long kk = ((unsigned long long)v << 32) | (unsigned)i;
                        kmin = kk < kmin ? kk : kmin;
                    }
                    gv[g] = kmin;
                }
            }
            unsigned long long nlm = gv[0];
#pragma unroll
            for (int g = 1; g < 8; ++g) nlm = gv[g] < nlm ? gv[g] : nlm;
            lm = nlm;
        }
    }
}

// ---------------- gather: sums + std partials + ef' (bf16) fused ------------
__global__ __launch_bounds__(128) void gather_kernel(const float* __restrict__ xn,
                                                     const int* __restrict__ idxb,
                                                     const float* __restrict__ alpha,
                                                     unsigned short* __restrict__ efp,
                                                     float2* __restrict__ part) {
    int q = blockIdx.x;
    int b = q >> 11;
    int t = threadIdx.x;
    __shared__ int sidx[8];
    if (t < 8) sidx[t] = idxb[(size_t)q * 8 + t];
    __syncthreads();
    const float* xno = xn + ((size_t)b * 2049 + 1) * C384;
    const float* xc  = xn + ((size_t)q + b + 1) * C384;
    float s1 = 0.f, s2 = 0.f;
    for (int c = t; c < C384; c += 128) {
        float xcv = xc[c];
        float acc = 0.f;
#pragma unroll
        for (int k = 0; k < 8; ++k) {
            float v = xno[(size_t)sidx[k] * C384 + c];
            acc += v;
            float d = v - xcv;
            s1 += d;
            s2 += d * d;
        }
        float mk = acc * 0.125f;
        efp[(size_t)q * 768 + c]       = f2bf(alpha[c] * (mk - xcv));
        efp[(size_t)q * 768 + 384 + c] = f2bf(alpha[384 + c] * xcv);
    }
    __shared__ float r1[128], r2[128];
    r1[t] = s1; r2[t] = s2;
    __syncthreads();
#pragma unroll
    for (int s = 64; s; s >>= 1) {
        if (t < s) { r1[t] += r1[t + s]; r2[t] += r2[t + s]; }
        __syncthreads();
    }
    if (t == 0) part[q] = make_float2(r1[0], r2[0]);
}

// ---------------- reduce std partials -> inv = 1/(std+1e-5) -----------------
__global__ __launch_bounds__(256) void std_kernel(const float2* __restrict__ part,
                                                  float* __restrict__ stdbuf) {
    int t = threadIdx.x;
    double s1 = 0.0, s2 = 0.0;
    for (int i = t; i < 8192; i += 256) {
        float2 p = part[i];
        s1 += (double)p.x;
        s2 += (double)p.y;
    }
    __shared__ double r1[256], r2[256];
    r1[t] = s1; r2[t] = s2;
    __syncthreads();
#pragma unroll
    for (int s = 128; s; s >>= 1) {
        if (t < s) { r1[t] += r1[t + s]; r2[t] += r2[t + s]; }
        __syncthreads();
    }
    if (t == 0) {
        const double N = 25165824.0;
        double var = (r2[0] - r1[0] * r1[0] / N) / (N - 1.0);
        float stdf = (float)sqrt(var);
        stdbuf[0] = 1.0f / (stdf + 1e-5f);
    }
}

// ---------------- cls rows ----------------------------------------------------
__global__ void cls_kernel(const float* __restrict__ x,
                           const float* __restrict__ xn,
                           float* __restrict__ out) {
    int b = blockIdx.x;
    int c = threadIdx.x;
    size_t r = (size_t)b * 2049 * C384 + c;
    out[r] = x[r] + xn[r];
}

// ---------------- bf16 MFMA GEMM, 64x64 tile, BK=64, double-buffered ---------
// R6 schedule; in-loop barrier = lgkmcnt(0)+s_barrier ONLY (no vmcnt drain),
// so tile t+1's global loads stay in flight across the barrier and land
// under compute(t); the vmcnt wait occurs at the ds_write register dep.
#define ST_STR 68

template <bool GELU, bool REMAP, bool RES, bool OUTBF>
__global__ __launch_bounds__(256) void mfma_gemm(const unsigned short* __restrict__ A,
                                                 const unsigned short* __restrict__ Bt,
                                                 const float* __restrict__ bias,
                                                 const float* __restrict__ res,
                                                 void* __restrict__ outp,
                                                 int M, int N, int K, int ntn) {
    __shared__ char smem[32768];
    int t = threadIdx.x;
    int lane = t & 63, w = t >> 6;
    int wr = w >> 1, wc = w & 1;

    int nwg = gridDim.x;
    int q8 = nwg >> 3, r8 = nwg & 7;
    int xcd = blockIdx.x & 7, idx = blockIdx.x >> 3;
    int lid = (xcd < r8 ? xcd * (q8 + 1) : r8 * (q8 + 1) + (xcd - r8) * q8) + idx;
    int by = lid / ntn, bx = lid - by * ntn;
    int bm = by * 64, bn = bx * 64;

    f32x4 acc[2][2] = {};

    int srow = t >> 3;
    int sc16 = t & 7;
    int swz = (sc16 ^ (srow & 7)) << 4;

    const unsigned short* pa0 = A + (size_t)(bm + srow) * K + sc16 * 8;
    const unsigned short* pa1 = A + (size_t)(bm + srow + 32) * K + sc16 * 8;
    const unsigned short* pb0 = Bt + (size_t)(bn + srow) * K + sc16 * 8;
    const unsigned short* pb1 = Bt + (size_t)(bn + srow + 32) * K + sc16 * 8;
    bool ok0 = (bm + srow) < M, ok1 = (bm + srow + 32) < M;
    const uint4 zz = make_uint4(0u, 0u, 0u, 0u);

    uint4 va0, va1, vb0, vb1;
    auto stage = [&](char* dst) {
        *(uint4*)(dst + srow * 128 + swz) = va0;
        *(uint4*)(dst + (srow + 32) * 128 + swz) = va1;
        char* dB = dst + 8192;
        *(uint4*)(dB + srow * 128 + swz) = vb0;
        *(uint4*)(dB + (srow + 32) * 128 + swz) = vb1;
    };
    auto loadt = [&](int tile) {
        int ko = tile << 6;
        va0 = ok0 ? *(const uint4*)(pa0 + ko) : zz;
        va1 = ok1 ? *(const uint4*)(pa1 + ko) : zz;
        vb0 = *(const uint4*)(pb0 + ko);
        vb1 = *(const uint4*)(pb1 + ko);
    };
    auto compute = [&](const char* smA) {
        const char* smB = smA + 8192;
#pragma unroll
        for (int ks = 0; ks < 2; ++ks) {
            short8 af[2], bfr[2];
            int cb = ks * 4 + (lane >> 4);
#pragma unroll
            for (int mi = 0; mi < 2; ++mi) {
                int row = wr * 32 + mi * 16 + (lane & 15);
                af[mi] = *(const short8*)(smA + row * 128 + ((cb ^ (row & 7)) << 4));
            }
#pragma unroll
            for (int nj = 0; nj < 2; ++nj) {
                int row = wc * 32 + nj * 16 + (lane & 15);
                bfr[nj] = *(const short8*)(smB + row * 128 + ((cb ^ (row & 7)) << 4));
            }
#pragma unroll
            for (int mi = 0; mi < 2; ++mi)
#pragma unroll
                for (int nj = 0; nj < 2; ++nj)
                    acc[mi][nj] = __builtin_amdgcn_mfma_f32_16x16x32_bf16(
                        af[mi], bfr[nj], acc[mi][nj], 0, 0, 0);
        }
    };

    int nt = K >> 6;
    // prologue: stage tile0 -> buf0; issue tile1 loads; LDS barrier.
    loadt(0);
    stage(smem);
    if (nt > 1) loadt(1);
    asm volatile("s_waitcnt lgkmcnt(0)" ::: "memory");
    __builtin_amdgcn_s_barrier();
    asm volatile("" ::: "memory");

    for (int tix = 0; tix < nt; ++tix) {
        char* base = smem + (tix & 1) * 16384;
        compute(base);                        // read buf[cur]
        if (tix + 1 < nt) {
            stage(smem + ((tix + 1) & 1) * 16384);   // write buf[cur^1] (t+1)
            if (tix + 2 < nt) loadt(tix + 2);        // loads stay in flight
        }
        asm volatile("s_waitcnt lgkmcnt(0)" ::: "memory");
        __builtin_amdgcn_s_barrier();
        asm volatile("" ::: "memory");
    }

    // ---- epilogue: stage f32 tile in LDS, then coalesced full-line stores ----
    float* st = (float*)smem;
#pragma unroll
    for (int nj = 0; nj < 2; ++nj) {
        int nl = wc * 32 + nj * 16 + (lane & 15);
        float bs = bias[bn + nl];
#pragma unroll
        for (int mi = 0; mi < 2; ++mi) {
#pragma unroll
            for (int r = 0; r < 4; ++r) {
                int ml = wr * 32 + mi * 16 + (lane >> 4) * 4 + r;
                float v = acc[mi][nj][r] + bs;
                if (GELU) v = gelu_exact(v);
                st[ml * ST_STR + nl] = v;
            }
        }
    }
    __syncthreads();
    if (OUTBF) {
#pragma unroll
        for (int i = 0; i < 2; ++i) {
            int chunk = t + i * 256;
            int ml = chunk >> 3, c8 = (chunk & 7) * 8;
            int m = bm + ml;
            if (m < M) {
                unsigned short tmp[8];
#pragma unroll
                for (int j = 0; j < 8; ++j) tmp[j] = f2bf(st[ml * ST_STR + c8 + j]);
                *(uint4*)((unsigned short*)outp + (size_t)m * N + bn + c8) = *(uint4*)tmp;
            }
        }
    } else {
#pragma unroll
        for (int i = 0; i < 4; ++i) {
            int chunk = t + i * 256;
            int ml = chunk >> 4, c4 = (chunk & 15) * 4;
            int m = bm + ml;
            if (m < M) {
                size_t orow = REMAP ? (size_t)(m + (m >> 11) + 1) : (size_t)m;
                size_t off = orow * (size_t)N + bn + c4;
                float4 v = *(float4*)&st[ml * ST_STR + c4];
                if (RES) {
                    float4 rv = *(const float4*)(res + off);
                    v.x += rv.x; v.y += rv.y; v.z += rv.z; v.w += rv.w;
                }
                *(float4*)((float*)outp + off) = v;
            }
        }
    }
}

// ---------------------------------------------------------------------------
extern "C" void kernel_launch(void* const* d_in, const int* in_sizes, int n_in,
                              void* d_out, int out_size, void* d_ws, size_t ws_size,
                              hipStream_t stream) {
    const float* center  = (const float*)d_in[0];
    const float* x       = (const float*)d_in[1];
    const float* ln1_g   = (const float*)d_in[2];
    const float* ln1_b   = (const float*)d_in[3];
    const float* alpha   = (const float*)d_in[4];
    const float* beta    = (const float*)d_in[5];
    const float* attn_w1 = (const float*)d_in[6];
    const float* attn_b1 = (const float*)d_in[7];
    const float* attn_w2 = (const float*)d_in[8];
    const float* attn_b2 = (const float*)d_in[9];
    const float* ln2_g   = (const float*)d_in[10];
    const float* ln2_b   = (const float*)d_in[11];
    const float* mlp_w1  = (const float*)d_in[12];
    const float* mlp_b1  = (const float*)d_in[13];
    const float* mlp_w2  = (const float*)d_in[14];
    const float* mlp_b2  = (const float*)d_in[15];
    float* out = (float*)d_out;

    // workspace layout (bytes; g overlays dead xn/efp region)
    char* wsb = (char*)d_ws;
    float*          xn     = (float*)(wsb + 0);                  // 12,589,056 (ln1->cls)
    unsigned short* efp    = (unsigned short*)(wsb + 12589056);  // 12,582,912 (gather->gemm1)
    int*            idxb   = (int*)(wsb + 25171968);             // 262,144
    float2*         part   = (float2*)(wsb + 25434112);          // 65,536
    float*          stdbuf = (float*)(wsb + 25499648);           // 256
    float4*         pts4   = (float4*)(wsb + 25499904);          // 131,072
    float*          cv     = (float*)(wsb + 25630976);           // 1,536
    unsigned short* h1     = (unsigned short*)(wsb + 25632512);  // 6,291,456 (gemm1->gemm2)
    unsigned short* yb     = (unsigned short*)(wsb + 31923968);  // 6,294,528 (ln2->gemm3)
    unsigned short* g      = (unsigned short*)(wsb + 0);         // 25,178,112 overlay (gemm3->gemm4)
    unsigned short* w1T    = (unsigned short*)(wsb + 38218496);  // 589,824
    unsigned short* w2T    = (unsigned short*)(wsb + 38808320);  // 294,912
    unsigned short* mw1T   = (unsigned short*)(wsb + 39103232);  // 1,179,648
    unsigned short* mw2T   = (unsigned short*)(wsb + 40282880);  // 1,179,648 -> 41,462,528
    float*          cvpart = (float*)(wsb + 41462528);           // 49,152

    // 0. prep: transposes + pts4 + cv partials
    prep_kernel<<<1520, 256, 0, stream>>>(attn_w2, mlp_w1, mlp_w2, center, beta,
                                          attn_w1, w2T, mw1T, mw2T, pts4, cvpart);
    // 0b. cv reduce
    cvreduce_kernel<<<1, 384, 0, stream>>>(cvpart, attn_b1, cv);
    // 1. LN1 (f32)
    ln_kernel<false><<<2049, 256, 0, stream>>>(x, xn, ln1_g, ln1_b);
    // 2. KNN
    knn_kernel<<<2048, 256, 0, stream>>>(pts4, idxb);
    // 3. gather (+fused ef')
    gather_kernel<<<8192, 128, 0, stream>>>(xn, idxb, alpha, efp, part);
    // 4. std -> inv
    std_kernel<<<1, 256, 0, stream>>>(part, stdbuf);
    // 5. W1 transpose+cast with inv on top half
    tcastw1_kernel<<<288, 256, 0, stream>>>(attn_w1, stdbuf, w1T);
    // 6. h1 = gelu(ef' @ w1T + cv)       M=8192 N=384 K=768  (128 x 6)
    mfma_gemm<true, false, false, true><<<768, 256, 0, stream>>>(
        efp, w1T, cv, nullptr, h1, 8192, 384, 768, 6);
    // 7. out[remap] = x + h1 @ w2T + b2  M=8192 N=384 K=384
    mfma_gemm<false, true, true, false><<<768, 256, 0, stream>>>(
        h1, w2T, attn_b2, x, out, 8192, 384, 384, 6);
    // 7b. cls rows
    cls_kernel<<<4, 384, 0, stream>>>(x, xn, out);
    // 8. LN2 -> yb bf16
    ln_kernel<true><<<2049, 256, 0, stream>>>(out, yb, ln2_g, ln2_b);
    // 9. g = gelu(yb @ mw1T + b1)        M=8196 N=1536 K=384  (129 x 24)
    mfma_gemm<true, false, false, true><<<3096, 256, 0, stream>>>(
        yb, mw1T, mlp_b1, nullptr, g, 8196, 1536, 384, 24);
    // 10. out += g @ mw2T + b2           M=8196 N=384 K=1536  (129 x 6)
    mfma_gemm<false, false, true, false><<<774, 256, 0, stream>>>(
        g, mw2T, mlp_b2, out, out, 8196, 384, 1536, 6);
}

// Round 12
// 143.681 us; speedup vs baseline: 1.4434x; 1.0349x over previous
//
#include <hip/hip_runtime.h>
#include <math.h>

// ---------------------------------------------------------------------------
// Mamba3DBlock forward. B=4, Npts=2048, C=384, K_GROUP=8. x rows = 8196.
// R12: GEMM reverted to R9 __syncthreads schedule (R11's inline-asm barrier
//      cost ~14us of compiler scheduling); cls fused into LN2; cv k-split.
// ---------------------------------------------------------------------------

#define C384 384

typedef __attribute__((ext_vector_type(8))) short short8;
typedef __attribute__((ext_vector_type(4))) float f32x4;

__device__ __forceinline__ float gelu_exact(float v) {
    return 0.5f * v * (1.0f + erff(v * 0.7071067811865475f));
}

__device__ __forceinline__ unsigned short f2bf(float f) {
    unsigned u = __float_as_uint(f);
    u += 0x7fffu + ((u >> 16) & 1u);
    return (unsigned short)(u >> 16);
}

// ---------------- LN1: one wave per row, no barriers -------------------------
__global__ __launch_bounds__(256) void ln_kernel(const float* __restrict__ in,
                                                 float* __restrict__ outp,
                                                 const float* __restrict__ gw,
                                                 const float* __restrict__ bw) {
    int w = threadIdx.x >> 6, l = threadIdx.x & 63;
    int row = blockIdx.x * 4 + w;
    const float* x = in + (size_t)row * C384;
    float v[6];
    float s = 0.f;
#pragma unroll
    for (int i = 0; i < 6; ++i) { v[i] = x[l + 64 * i]; s += v[i]; }
#pragma unroll
    for (int off = 32; off; off >>= 1) s += __shfl_xor(s, off, 64);
    float m = s * (1.0f / 384.0f);
    float s2 = 0.f;
#pragma unroll
    for (int i = 0; i < 6; ++i) { v[i] -= m; s2 += v[i] * v[i]; }
#pragma unroll
    for (int off = 32; off; off >>= 1) s2 += __shfl_xor(s2, off, 64);
    float rstd = 1.0f / sqrtf(s2 * (1.0f / 384.0f) + 1e-5f);
#pragma unroll
    for (int i = 0; i < 6; ++i) {
        int c = l + 64 * i;
        outp[(size_t)row * C384 + c] = v[i] * rstd * gw[c] + bw[c];
    }
}

// ---------------- LN2 (+cls fusion): bf16 out; cls rows get out=x+xn first ---
__global__ __launch_bounds__(256) void ln2_kernel(const float* __restrict__ x,
                                                  const float* __restrict__ xn,
                                                  float* __restrict__ out,
                                                  unsigned short* __restrict__ yb,
                                                  const float* __restrict__ gw,
                                                  const float* __restrict__ bw) {
    int w = threadIdx.x >> 6, l = threadIdx.x & 63;
    int row = blockIdx.x * 4 + w;
    float v[6];
    if ((row & 2047) == (row >> 11)) {      // row % 2049 == 0 for row < 4*2049
        const float* xr = x + (size_t)row * C384;
        const float* xnr = xn + (size_t)row * C384;
        float* orow = out + (size_t)row * C384;
#pragma unroll
        for (int i = 0; i < 6; ++i) {
            int c = l + 64 * i;
            float o = xr[c] + xnr[c];
            orow[c] = o;
            v[i] = o;
        }
    } else {
        const float* src = out + (size_t)row * C384;
#pragma unroll
        for (int i = 0; i < 6; ++i) v[i] = src[l + 64 * i];
    }
    float s = 0.f;
#pragma unroll
    for (int i = 0; i < 6; ++i) s += v[i];
#pragma unroll
    for (int off = 32; off; off >>= 1) s += __shfl_xor(s, off, 64);
    float m = s * (1.0f / 384.0f);
    float s2 = 0.f;
#pragma unroll
    for (int i = 0; i < 6; ++i) { v[i] -= m; s2 += v[i] * v[i]; }
#pragma unroll
    for (int off = 32; off; off >>= 1) s2 += __shfl_xor(s2, off, 64);
    float rstd = 1.0f / sqrtf(s2 * (1.0f / 384.0f) + 1e-5f);
#pragma unroll
    for (int i = 0; i < 6; ++i) {
        int c = l + 64 * i;
        yb[(size_t)row * C384 + c] = f2bf(v[i] * rstd * gw[c] + bw[c]);
    }
}

// ---------------- prep: transposes + pts4 + cv partials (k-split) -----------
__global__ __launch_bounds__(256) void prep_kernel(const float* __restrict__ w2,
                                                   const float* __restrict__ m1,
                                                   const float* __restrict__ m2,
                                                   const float* __restrict__ center,
                                                   const float* __restrict__ beta,
                                                   const float* __restrict__ w1,
                                                   unsigned short* __restrict__ o2,
                                                   unsigned short* __restrict__ o3,
                                                   unsigned short* __restrict__ o4,
                                                   float4* __restrict__ pts,
                                                   float* __restrict__ cvpart) {
    int tid = blockIdx.x;
    if (tid < 1296) {
        const float* in; unsigned short* outp; int K, N, local;
        if (tid < 144)      { in = w2; outp = o2; K = 384;  N = 384;  local = tid; }
        else if (tid < 720) { in = m1; outp = o3; K = 384;  N = 1536; local = tid - 144; }
        else                { in = m2; outp = o4; K = 1536; N = 384;  local = tid - 720; }
        int ntN = N >> 5;
        int kb = (local / ntN) * 32, nb = (local % ntN) * 32;
        __shared__ float tile[32][33];
        int c = threadIdx.x & 31, r0 = threadIdx.x >> 5;
#pragma unroll
        for (int i = 0; i < 4; ++i) {
            int r = r0 + i * 8;
            tile[r][c] = in[(size_t)(kb + r) * N + nb + c];
        }
        __syncthreads();
#pragma unroll
        for (int i = 0; i < 4; ++i) {
            int r = r0 + i * 8;
            outp[(size_t)(nb + r) * K + kb + c] = f2bf(tile[c][r]);
        }
    } else if (tid < 1328) {
        int p = (tid - 1296) * 256 + threadIdx.x;    // 0..8191
        float cx = center[p * 3], cy = center[p * 3 + 1], cz = center[p * 3 + 2];
        float sq = cx * cx + cy * cy + cz * cz;
        pts[p] = make_float4(cx, cy, cz, sq);
    } else {
        // cv partials: 192 blocks = 32 k-splits x 6 n-blocks, 24 k each
        int local = tid - 1328;                      // 0..191
        int nblk = local % 6, ks = local / 6;
        if (threadIdx.x < 64) {
            int n = nblk * 64 + threadIdx.x;
            float s = 0.f;
            int k0 = ks * 24;
#pragma unroll
            for (int j = 0; j < 24; ++j)
                s = fmaf(beta[k0 + j], w1[(size_t)(k0 + j) * 384 + n], s);
            cvpart[(size_t)ks * 384 + n] = s;
        }
    }
}

// ---------------- cv reduce: cv[n] = b1[n] + sum_ks cvpart[ks][n] -----------
__global__ __launch_bounds__(384) void cvreduce_kernel(const float* __restrict__ cvpart,
                                                       const float* __restrict__ b1,
                                                       float* __restrict__ cv) {
    int n = threadIdx.x;
    float s = b1[n];
#pragma unroll
    for (int ks = 0; ks < 32; ++ks) s += cvpart[(size_t)ks * 384 + n];
    cv[n] = s;
}

// ---------------- W1 transpose+cast with inv folded into top K-half ---------
__global__ __launch_bounds__(256) void tcastw1_kernel(const float* __restrict__ w1,
                                                      const float* __restrict__ stdbuf,
                                                      unsigned short* __restrict__ o1) {
    int tid = blockIdx.x;                    // 288 tiles: K=768 x N=384
    int kb = (tid / 12) * 32, nb = (tid % 12) * 32;
    float scale = (kb < 384) ? stdbuf[0] : 1.0f;
    __shared__ float tile[32][33];
    int c = threadIdx.x & 31, r0 = threadIdx.x >> 5;
#pragma unroll
    for (int i = 0; i < 4; ++i) {
        int r = r0 + i * 8;
        tile[r][c] = w1[(size_t)(kb + r) * 384 + nb + c];
    }
    __syncthreads();
#pragma unroll
    for (int i = 0; i < 4; ++i) {
        int r = r0 + i * 8;
        o1[(size_t)(nb + r) * 768 + kb + c] = f2bf(tile[c][r] * scale);
    }
}

// ---------------- KNN: one wave per query, pts4 + group-min cache -----------
__global__ __launch_bounds__(256) void knn_kernel(const float4* __restrict__ pts,
                                                  int* __restrict__ idx_out) {
    int w = threadIdx.x >> 6;
    int l = threadIdx.x & 63;
    int q = blockIdx.x * 4 + w;
    int b = q >> 11, n = q & 2047;
    const float4* pb = pts + (size_t)b * 2048;
    float4 qp = pb[n];
    float sqq = qp.w;
    unsigned val[32];
    unsigned long long gv[8];
#pragma unroll
    for (int g = 0; g < 8; ++g) {
        unsigned long long kmin = ~0ULL;
#pragma unroll
        for (int j = 0; j < 4; ++j) {
            int i = g * 4 + j;
            float4 c = pb[i * 64 + l];
            float dot = qp.x * c.x + qp.y * c.y + qp.z * c.z;
            float d2 = (sqq + c.w) - 2.0f * dot;
            unsigned u = __float_as_uint(d2);
            u ^= (unsigned)(((int)u >> 31) | 0x80000000);
            val[i] = u;
            unsigned long long kk = ((unsigned long long)u << 32) | (unsigned)i;
            kmin = kk < kmin ? kk : kmin;
        }
        gv[g] = kmin;
    }
    unsigned long long lm = gv[0];
#pragma unroll
    for (int g = 1; g < 8; ++g) lm = gv[g] < lm ? gv[g] : lm;

    for (int sel = 0; sel < 8; ++sel) {
        unsigned wval = (unsigned)(lm >> 32);
        unsigned wmin = wval;
#pragma unroll
        for (int off = 32; off; off >>= 1) {
            unsigned o = (unsigned)__shfl_xor((int)wmin, off, 64);
            wmin = o < wmin ? o : wmin;
        }
        bool eligible = (wval == wmin);
        unsigned long long mask = __ballot(eligible);
        unsigned myM = ((unsigned)lm) * 64u + (unsigned)l;
        if (__popcll(mask) > 1) {
            unsigned mc = eligible ? myM : 0xFFFFFFFFu;
#pragma unroll
            for (int off = 32; off; off >>= 1) {
                unsigned o = (unsigned)__shfl_xor((int)mc, off, 64);
                mc = o < mc ? o : mc;
            }
            eligible = eligible && (myM == mc);
        }
        if (eligible) {
            idx_out[(size_t)q * 8 + sel] = (int)myM;
            unsigned ws = (unsigned)lm;
#pragma unroll
            for (int g = 0; g < 8; ++g) {
                if (gv[g] == lm) {
                    asm volatile("" ::: "memory");
                    unsigned long long kmin = ~0ULL;
#pragma unroll
                    for (int j = 0; j < 4; ++j) {
                        int i = g * 4 + j;
                        unsigned v = ((unsigned)i == ws) ? 0xFFFFFFFFu : val[i];
                        val[i] = v;
                        unsigned long long kk = ((unsigned long long)v << 32) | (unsigned)i;
                        kmin = kk < kmin ? kk : kmin;
                    }
                    gv[g] = kmin;
                }
            }
            unsigned long long nlm = gv[0];
#pragma unroll
            for (int g = 1; g < 8; ++g) nlm = gv[g] < nlm ? gv[g] : nlm;
            lm = nlm;
        }
    }
}

// ---------------- gather: sums + std partials + ef' (bf16) fused ------------
__global__ __launch_bounds__(128) void gather_kernel(const float* __restrict__ xn,
                                                     const int* __restrict__ idxb,
                                                     const float* __restrict__ alpha,
                                                     unsigned short* __restrict__ efp,
                                                     float2* __restrict__ part) {
    int q = blockIdx.x;
    int b = q >> 11;
    int t = threadIdx.x;
    __shared__ int sidx[8];
    if (t < 8) sidx[t] = idxb[(size_t)q * 8 + t];
    __syncthreads();
    const float* xno = xn + ((size_t)b * 2049 + 1) * C384;
    const float* xc  = xn + ((size_t)q + b + 1) * C384;
    float s1 = 0.f, s2 = 0.f;
    for (int c = t; c < C384; c += 128) {
        float xcv = xc[c];
        float acc = 0.f;
#pragma unroll
        for (int k = 0; k < 8; ++k) {
            float v = xno[(size_t)sidx[k] * C384 + c];
            acc += v;
            float d = v - xcv;
            s1 += d;
            s2 += d * d;
        }
        float mk = acc * 0.125f;
        efp[(size_t)q * 768 + c]       = f2bf(alpha[c] * (mk - xcv));
        efp[(size_t)q * 768 + 384 + c] = f2bf(alpha[384 + c] * xcv);
    }
    __shared__ float r1[128], r2[128];
    r1[t] = s1; r2[t] = s2;
    __syncthreads();
#pragma unroll
    for (int s = 64; s; s >>= 1) {
        if (t < s) { r1[t] += r1[t + s]; r2[t] += r2[t + s]; }
        __syncthreads();
    }
    if (t == 0) part[q] = make_float2(r1[0], r2[0]);
}

// ---------------- reduce std partials -> inv = 1/(std+1e-5) -----------------
__global__ __launch_bounds__(256) void std_kernel(const float2* __restrict__ part,
                                                  float* __restrict__ stdbuf) {
    int t = threadIdx.x;
    double s1 = 0.0, s2 = 0.0;
    for (int i = t; i < 8192; i += 256) {
        float2 p = part[i];
        s1 += (double)p.x;
        s2 += (double)p.y;
    }
    __shared__ double r1[256], r2[256];
    r1[t] = s1; r2[t] = s2;
    __syncthreads();
#pragma unroll
    for (int s = 128; s; s >>= 1) {
        if (t < s) { r1[t] += r1[t + s]; r2[t] += r2[t + s]; }
        __syncthreads();
    }
    if (t == 0) {
        const double N = 25165824.0;
        double var = (r2[0] - r1[0] * r1[0] / N) / (N - 1.0);
        float stdf = (float)sqrt(var);
        stdbuf[0] = 1.0f / (stdf + 1e-5f);
    }
}

// ---------------- bf16 MFMA GEMM, 64x64 tile, BK=64, double-buffered ---------
// R9/R6-proven schedule: loads issued, __syncthreads, compute, ds_write.
#define ST_STR 68

template <bool GELU, bool REMAP, bool RES, bool OUTBF>
__global__ __launch_bounds__(256) void mfma_gemm(const unsigned short* __restrict__ A,
                                                 const unsigned short* __restrict__ Bt,
                                                 const float* __restrict__ bias,
                                                 const float* __restrict__ res,
                                                 void* __restrict__ outp,
                                                 int M, int N, int K, int ntn) {
    __shared__ char smem[32768];
    int t = threadIdx.x;
    int lane = t & 63, w = t >> 6;
    int wr = w >> 1, wc = w & 1;

    int nwg = gridDim.x;
    int q8 = nwg >> 3, r8 = nwg & 7;
    int xcd = blockIdx.x & 7, idx = blockIdx.x >> 3;
    int lid = (xcd < r8 ? xcd * (q8 + 1) : r8 * (q8 + 1) + (xcd - r8) * q8) + idx;
    int by = lid / ntn, bx = lid - by * ntn;
    int bm = by * 64, bn = bx * 64;

    f32x4 acc[2][2] = {};

    int srow = t >> 3;
    int sc16 = t & 7;
    int swz = (sc16 ^ (srow & 7)) << 4;

    const unsigned short* pa0 = A + (size_t)(bm + srow) * K + sc16 * 8;
    const unsigned short* pa1 = A + (size_t)(bm + srow + 32) * K + sc16 * 8;
    const unsigned short* pb0 = Bt + (size_t)(bn + srow) * K + sc16 * 8;
    const unsigned short* pb1 = Bt + (size_t)(bn + srow + 32) * K + sc16 * 8;
    bool ok0 = (bm + srow) < M, ok1 = (bm + srow + 32) < M;

    uint4 va0, va1, vb0, vb1;
    const uint4 zz = make_uint4(0u, 0u, 0u, 0u);
    va0 = ok0 ? *(const uint4*)pa0 : zz;
    va1 = ok1 ? *(const uint4*)pa1 : zz;
    vb0 = *(const uint4*)pb0;
    vb1 = *(const uint4*)pb1;
    {
        char* smA = smem;
        char* smB = smem + 8192;
        *(uint4*)(smA + srow * 128 + swz) = va0;
        *(uint4*)(smA + (srow + 32) * 128 + swz) = va1;
        *(uint4*)(smB + srow * 128 + swz) = vb0;
        *(uint4*)(smB + (srow + 32) * 128 + swz) = vb1;
    }

    int nt = K >> 6;
    for (int tix = 0; tix < nt; ++tix) {
        int cur = tix & 1;
        char* smA = smem + cur * 16384;
        char* smB = smA + 8192;
        if (tix + 1 < nt) {
            int ko = (tix + 1) << 6;
            va0 = ok0 ? *(const uint4*)(pa0 + ko) : zz;
            va1 = ok1 ? *(const uint4*)(pa1 + ko) : zz;
            vb0 = *(const uint4*)(pb0 + ko);
            vb1 = *(const uint4*)(pb1 + ko);
        }
        __syncthreads();
#pragma unroll
        for (int ks = 0; ks < 2; ++ks) {
            short8 af[2], bfr[2];
            int cb = ks * 4 + (lane >> 4);
#pragma unroll
            for (int mi = 0; mi < 2; ++mi) {
                int row = wr * 32 + mi * 16 + (lane & 15);
                af[mi] = *(const short8*)(smA + row * 128 + ((cb ^ (row & 7)) << 4));
            }
#pragma unroll
            for (int nj = 0; nj < 2; ++nj) {
                int row = wc * 32 + nj * 16 + (lane & 15);
                bfr[nj] = *(const short8*)(smB + row * 128 + ((cb ^ (row & 7)) << 4));
            }
#pragma unroll
            for (int mi = 0; mi < 2; ++mi)
#pragma unroll
                for (int nj = 0; nj < 2; ++nj)
                    acc[mi][nj] = __builtin_amdgcn_mfma_f32_16x16x32_bf16(
                        af[mi], bfr[nj], acc[mi][nj], 0, 0, 0);
        }
        if (tix + 1 < nt) {
            char* dA = smem + (cur ^ 1) * 16384;
            char* dB = dA + 8192;
            *(uint4*)(dA + srow * 128 + swz) = va0;
            *(uint4*)(dA + (srow + 32) * 128 + swz) = va1;
            *(uint4*)(dB + srow * 128 + swz) = vb0;
            *(uint4*)(dB + (srow + 32) * 128 + swz) = vb1;
        }
    }

    // ---- epilogue: stage f32 tile in LDS, then coalesced full-line stores ----
    __syncthreads();
    float* st = (float*)smem;
#pragma unroll
    for (int nj = 0; nj < 2; ++nj) {
        int nl = wc * 32 + nj * 16 + (lane & 15);
        float bs = bias[bn + nl];
#pragma unroll
        for (int mi = 0; mi < 2; ++mi) {
#pragma unroll
            for (int r = 0; r < 4; ++r) {
                int ml = wr * 32 + mi * 16 + (lane >> 4) * 4 + r;
                float v = acc[mi][nj][r] + bs;
                if (GELU) v = gelu_exact(v);
                st[ml * ST_STR + nl] = v;
            }
        }
    }
    __syncthreads();
    if (OUTBF) {
#pragma unroll
        for (int i = 0; i < 2; ++i) {
            int chunk = t + i * 256;
            int ml = chunk >> 3, c8 = (chunk & 7) * 8;
            int m = bm + ml;
            if (m < M) {
                unsigned short tmp[8];
#pragma unroll
                for (int j = 0; j < 8; ++j) tmp[j] = f2bf(st[ml * ST_STR + c8 + j]);
                *(uint4*)((unsigned short*)outp + (size_t)m * N + bn + c8) = *(uint4*)tmp;
            }
        }
    } else {
#pragma unroll
        for (int i = 0; i < 4; ++i) {
            int chunk = t + i * 256;
            int ml = chunk >> 4, c4 = (chunk & 15) * 4;
            int m = bm + ml;
            if (m < M) {
                size_t orow = REMAP ? (size_t)(m + (m >> 11) + 1) : (size_t)m;
                size_t off = orow * (size_t)N + bn + c4;
                float4 v = *(float4*)&st[ml * ST_STR + c4];
                if (RES) {
                    float4 rv = *(const float4*)(res + off);
                    v.x += rv.x; v.y += rv.y; v.z += rv.z; v.w += rv.w;
                }
                *(float4*)((float*)outp + off) = v;
            }
        }
    }
}

// ---------------------------------------------------------------------------
extern "C" void kernel_launch(void* const* d_in, const int* in_sizes, int n_in,
                              void* d_out, int out_size, void* d_ws, size_t ws_size,
                              hipStream_t stream) {
    const float* center  = (const float*)d_in[0];
    const float* x       = (const float*)d_in[1];
    const float* ln1_g   = (const float*)d_in[2];
    const float* ln1_b   = (const float*)d_in[3];
    const float* alpha   = (const float*)d_in[4];
    const float* beta    = (const float*)d_in[5];
    const float* attn_w1 = (const float*)d_in[6];
    const float* attn_b1 = (const float*)d_in[7];
    const float* attn_w2 = (const float*)d_in[8];
    const float* attn_b2 = (const float*)d_in[9];
    const float* ln2_g   = (const float*)d_in[10];
    const float* ln2_b   = (const float*)d_in[11];
    const float* mlp_w1  = (const float*)d_in[12];
    const float* mlp_b1  = (const float*)d_in[13];
    const float* mlp_w2  = (const float*)d_in[14];
    const float* mlp_b2  = (const float*)d_in[15];
    float* out = (float*)d_out;

    // workspace layout (bytes; g overlays dead xn/efp region)
    char* wsb = (char*)d_ws;
    float*          xn     = (float*)(wsb + 0);                  // 12,589,056 (ln1->ln2)
    unsigned short* efp    = (unsigned short*)(wsb + 12589056);  // 12,582,912 (gather->gemm1)
    int*            idxb   = (int*)(wsb + 25171968);             // 262,144
    float2*         part   = (float2*)(wsb + 25434112);          // 65,536
    float*          stdbuf = (float*)(wsb + 25499648);           // 256
    float4*         pts4   = (float4*)(wsb + 25499904);          // 131,072
    float*          cv     = (float*)(wsb + 25630976);           // 1,536
    unsigned short* h1     = (unsigned short*)(wsb + 25632512);  // 6,291,456 (gemm1->gemm2)
    unsigned short* yb     = (unsigned short*)(wsb + 31923968);  // 6,294,528 (ln2->gemm3)
    unsigned short* g      = (unsigned short*)(wsb + 0);         // 25,178,112 overlay (gemm3->gemm4)
    unsigned short* w1T    = (unsigned short*)(wsb + 38218496);  // 589,824
    unsigned short* w2T    = (unsigned short*)(wsb + 38808320);  // 294,912
    unsigned short* mw1T   = (unsigned short*)(wsb + 39103232);  // 1,179,648
    unsigned short* mw2T   = (unsigned short*)(wsb + 40282880);  // 1,179,648 -> 41,462,528
    float*          cvpart = (float*)(wsb + 41462528);           // 49,152

    // 0. prep: transposes + pts4 + cv partials
    prep_kernel<<<1520, 256, 0, stream>>>(attn_w2, mlp_w1, mlp_w2, center, beta,
                                          attn_w1, w2T, mw1T, mw2T, pts4, cvpart);
    // 0b. cv reduce
    cvreduce_kernel<<<1, 384, 0, stream>>>(cvpart, attn_b1, cv);
    // 1. LN1 (f32)
    ln_kernel<<<2049, 256, 0, stream>>>(x, xn, ln1_g, ln1_b);
    // 2. KNN
    knn_kernel<<<2048, 256, 0, stream>>>(pts4, idxb);
    // 3. gather (+fused ef')
    gather_kernel<<<8192, 128, 0, stream>>>(xn, idxb, alpha, efp, part);
    // 4. std -> inv
    std_kernel<<<1, 256, 0, stream>>>(part, stdbuf);
    // 5. W1 transpose+cast with inv on top half
    tcastw1_kernel<<<288, 256, 0, stream>>>(attn_w1, stdbuf, w1T);
    // 6. h1 = gelu(ef' @ w1T + cv)       M=8192 N=384 K=768  (128 x 6)
    mfma_gemm<true, false, false, true><<<768, 256, 0, stream>>>(
        efp, w1T, cv, nullptr, h1, 8192, 384, 768, 6);
    // 7. out[remap] = x + h1 @ w2T + b2  M=8192 N=384 K=384
    mfma_gemm<false, true, true, false><<<768, 256, 0, stream>>>(
        h1, w2T, attn_b2, x, out, 8192, 384, 384, 6);
    // 8. LN2 (+cls fusion) -> yb bf16
    ln2_kernel<<<2049, 256, 0, stream>>>(x, xn, out, yb, ln2_g, ln2_b);
    // 9. g = gelu(yb @ mw1T + b1)        M=8196 N=1536 K=384  (129 x 24)
    mfma_gemm<true, false, false, true><<<3096, 256, 0, stream>>>(
        yb, mw1T, mlp_b1, nullptr, g, 8196, 1536, 384, 24);
    // 10. out += g @ mw2T + b2           M=8196 N=384 K=1536  (129 x 6)
    mfma_gemm<false, false, true, false><<<774, 256, 0, stream>>>(
        g, mw2T, mlp_b2, out, out, 8196, 384, 1536, 6);
}

// Round 13
// 132.950 us; speedup vs baseline: 1.5599x; 1.0807x over previous
//
#include <hip/hip_runtime.h>
#include <math.h>

// ---------------------------------------------------------------------------
// Mamba3DBlock forward. B=4, Npts=2048, C=384, K_GROUP=8. x rows = 8196.
// R13: GEMM staging via global_load_lds width=16 (pre-swizzled global src,
//      linear LDS dest); LN1 merged into prep; cvreduce merged into std.
// ---------------------------------------------------------------------------

#define C384 384

typedef __attribute__((ext_vector_type(8))) short short8;
typedef __attribute__((ext_vector_type(4))) float f32x4;

__device__ __forceinline__ float gelu_exact(float v) {
    return 0.5f * v * (1.0f + erff(v * 0.7071067811865475f));
}

__device__ __forceinline__ unsigned short f2bf(float f) {
    unsigned u = __float_as_uint(f);
    u += 0x7fffu + ((u >> 16) & 1u);
    return (unsigned short)(u >> 16);
}

// ---------------- prep: LN1 + transposes + pts4 + cv partials ----------------
__global__ __launch_bounds__(256) void prep_kernel(const float* __restrict__ x,
                                                   const float* __restrict__ ln1g,
                                                   const float* __restrict__ ln1b,
                                                   float* __restrict__ xn,
                                                   const float* __restrict__ w2,
                                                   const float* __restrict__ m1,
                                                   const float* __restrict__ m2,
                                                   const float* __restrict__ center,
                                                   const float* __restrict__ beta,
                                                   const float* __restrict__ w1,
                                                   unsigned short* __restrict__ o2,
                                                   unsigned short* __restrict__ o3,
                                                   unsigned short* __restrict__ o4,
                                                   float4* __restrict__ pts,
                                                   float* __restrict__ cvpart) {
    int tid = blockIdx.x;
    if (tid < 2049) {
        // LN1: 4 rows per block, one wave per row
        int w = threadIdx.x >> 6, l = threadIdx.x & 63;
        int row = tid * 4 + w;
        const float* xr = x + (size_t)row * C384;
        float v[6];
        float s = 0.f;
#pragma unroll
        for (int i = 0; i < 6; ++i) { v[i] = xr[l + 64 * i]; s += v[i]; }
#pragma unroll
        for (int off = 32; off; off >>= 1) s += __shfl_xor(s, off, 64);
        float m = s * (1.0f / 384.0f);
        float s2 = 0.f;
#pragma unroll
        for (int i = 0; i < 6; ++i) { v[i] -= m; s2 += v[i] * v[i]; }
#pragma unroll
        for (int off = 32; off; off >>= 1) s2 += __shfl_xor(s2, off, 64);
        float rstd = 1.0f / sqrtf(s2 * (1.0f / 384.0f) + 1e-5f);
#pragma unroll
        for (int i = 0; i < 6; ++i) {
            int c = l + 64 * i;
            xn[(size_t)row * C384 + c] = v[i] * rstd * ln1g[c] + ln1b[c];
        }
    } else if (tid < 3345) {
        int local = tid - 2049;
        const float* in; unsigned short* outp; int K, N;
        if (local < 144)      { in = w2; outp = o2; K = 384;  N = 384; }
        else if (local < 720) { in = m1; outp = o3; K = 384;  N = 1536; local -= 144; }
        else                  { in = m2; outp = o4; K = 1536; N = 384;  local -= 720; }
        int ntN = N >> 5;
        int kb = (local / ntN) * 32, nb = (local % ntN) * 32;
        __shared__ float tile[32][33];
        int c = threadIdx.x & 31, r0 = threadIdx.x >> 5;
#pragma unroll
        for (int i = 0; i < 4; ++i) {
            int r = r0 + i * 8;
            tile[r][c] = in[(size_t)(kb + r) * N + nb + c];
        }
        __syncthreads();
#pragma unroll
        for (int i = 0; i < 4; ++i) {
            int r = r0 + i * 8;
            outp[(size_t)(nb + r) * K + kb + c] = f2bf(tile[c][r]);
        }
    } else if (tid < 3377) {
        int p = (tid - 3345) * 256 + threadIdx.x;    // 0..8191
        float cx = center[p * 3], cy = center[p * 3 + 1], cz = center[p * 3 + 2];
        float sq = cx * cx + cy * cy + cz * cz;
        pts[p] = make_float4(cx, cy, cz, sq);
    } else {
        // cv partials: 192 blocks = 32 k-splits x 6 n-blocks, 24 k each
        int local = tid - 3377;                      // 0..191
        int nblk = local % 6, ks = local / 6;
        if (threadIdx.x < 64) {
            int n = nblk * 64 + threadIdx.x;
            float s = 0.f;
            int k0 = ks * 24;
#pragma unroll
            for (int j = 0; j < 24; ++j)
                s = fmaf(beta[k0 + j], w1[(size_t)(k0 + j) * 384 + n], s);
            cvpart[(size_t)ks * 384 + n] = s;
        }
    }
}

// ---------------- std (block 0) + cv reduce (block 1) ------------------------
__global__ __launch_bounds__(256) void std_kernel(const float2* __restrict__ part,
                                                  float* __restrict__ stdbuf,
                                                  const float* __restrict__ cvpart,
                                                  const float* __restrict__ b1,
                                                  float* __restrict__ cv) {
    int t = threadIdx.x;
    if (blockIdx.x == 1) {
        for (int n = t; n < 384; n += 256) {
            float s = b1[n];
#pragma unroll
            for (int ks = 0; ks < 32; ++ks) s += cvpart[(size_t)ks * 384 + n];
            cv[n] = s;
        }
        return;
    }
    double s1 = 0.0, s2 = 0.0;
    for (int i = t; i < 8192; i += 256) {
        float2 p = part[i];
        s1 += (double)p.x;
        s2 += (double)p.y;
    }
    __shared__ double r1[256], r2[256];
    r1[t] = s1; r2[t] = s2;
    __syncthreads();
#pragma unroll
    for (int s = 128; s; s >>= 1) {
        if (t < s) { r1[t] += r1[t + s]; r2[t] += r2[t + s]; }
        __syncthreads();
    }
    if (t == 0) {
        const double N = 25165824.0;
        double var = (r2[0] - r1[0] * r1[0] / N) / (N - 1.0);
        float stdf = (float)sqrt(var);
        stdbuf[0] = 1.0f / (stdf + 1e-5f);
    }
}

// ---------------- LN2 (+cls fusion): bf16 out; cls rows get out=x+xn first ---
__global__ __launch_bounds__(256) void ln2_kernel(const float* __restrict__ x,
                                                  const float* __restrict__ xn,
                                                  float* __restrict__ out,
                                                  unsigned short* __restrict__ yb,
                                                  const float* __restrict__ gw,
                                                  const float* __restrict__ bw) {
    int w = threadIdx.x >> 6, l = threadIdx.x & 63;
    int row = blockIdx.x * 4 + w;
    float v[6];
    if ((row & 2047) == (row >> 11)) {      // row % 2049 == 0 for row < 4*2049
        const float* xr = x + (size_t)row * C384;
        const float* xnr = xn + (size_t)row * C384;
        float* orow = out + (size_t)row * C384;
#pragma unroll
        for (int i = 0; i < 6; ++i) {
            int c = l + 64 * i;
            float o = xr[c] + xnr[c];
            orow[c] = o;
            v[i] = o;
        }
    } else {
        const float* src = out + (size_t)row * C384;
#pragma unroll
        for (int i = 0; i < 6; ++i) v[i] = src[l + 64 * i];
    }
    float s = 0.f;
#pragma unroll
    for (int i = 0; i < 6; ++i) s += v[i];
#pragma unroll
    for (int off = 32; off; off >>= 1) s += __shfl_xor(s, off, 64);
    float m = s * (1.0f / 384.0f);
    float s2 = 0.f;
#pragma unroll
    for (int i = 0; i < 6; ++i) { v[i] -= m; s2 += v[i] * v[i]; }
#pragma unroll
    for (int off = 32; off; off >>= 1) s2 += __shfl_xor(s2, off, 64);
    float rstd = 1.0f / sqrtf(s2 * (1.0f / 384.0f) + 1e-5f);
#pragma unroll
    for (int i = 0; i < 6; ++i) {
        int c = l + 64 * i;
        yb[(size_t)row * C384 + c] = f2bf(v[i] * rstd * gw[c] + bw[c]);
    }
}

// ---------------- W1 transpose+cast with inv folded into top K-half ---------
__global__ __launch_bounds__(256) void tcastw1_kernel(const float* __restrict__ w1,
                                                      const float* __restrict__ stdbuf,
                                                      unsigned short* __restrict__ o1) {
    int tid = blockIdx.x;                    // 288 tiles: K=768 x N=384
    int kb = (tid / 12) * 32, nb = (tid % 12) * 32;
    float scale = (kb < 384) ? stdbuf[0] : 1.0f;
    __shared__ float tile[32][33];
    int c = threadIdx.x & 31, r0 = threadIdx.x >> 5;
#pragma unroll
    for (int i = 0; i < 4; ++i) {
        int r = r0 + i * 8;
        tile[r][c] = w1[(size_t)(kb + r) * 384 + nb + c];
    }
    __syncthreads();
#pragma unroll
    for (int i = 0; i < 4; ++i) {
        int r = r0 + i * 8;
        o1[(size_t)(nb + r) * 768 + kb + c] = f2bf(tile[c][r] * scale);
    }
}

// ---------------- KNN: one wave per query, pts4 + group-min cache -----------
__global__ __launch_bounds__(256) void knn_kernel(const float4* __restrict__ pts,
                                                  int* __restrict__ idx_out) {
    int w = threadIdx.x >> 6;
    int l = threadIdx.x & 63;
    int q = blockIdx.x * 4 + w;
    int b = q >> 11, n = q & 2047;
    const float4* pb = pts + (size_t)b * 2048;
    float4 qp = pb[n];
    float sqq = qp.w;
    unsigned val[32];
    unsigned long long gv[8];
#pragma unroll
    for (int g = 0; g < 8; ++g) {
        unsigned long long kmin = ~0ULL;
#pragma unroll
        for (int j = 0; j < 4; ++j) {
            int i = g * 4 + j;
            float4 c = pb[i * 64 + l];
            float dot = qp.x * c.x + qp.y * c.y + qp.z * c.z;
            float d2 = (sqq + c.w) - 2.0f * dot;
            unsigned u = __float_as_uint(d2);
            u ^= (unsigned)(((int)u >> 31) | 0x80000000);
            val[i] = u;
            unsigned long long kk = ((unsigned long long)u << 32) | (unsigned)i;
            kmin = kk < kmin ? kk : kmin;
        }
        gv[g] = kmin;
    }
    unsigned long long lm = gv[0];
#pragma unroll
    for (int g = 1; g < 8; ++g) lm = gv[g] < lm ? gv[g] : lm;

    for (int sel = 0; sel < 8; ++sel) {
        unsigned wval = (unsigned)(lm >> 32);
        unsigned wmin = wval;
#pragma unroll
        for (int off = 32; off; off >>= 1) {
            unsigned o = (unsigned)__shfl_xor((int)wmin, off, 64);
            wmin = o < wmin ? o : wmin;
        }
        bool eligible = (wval == wmin);
        unsigned long long mask = __ballot(eligible);
        unsigned myM = ((unsigned)lm) * 64u + (unsigned)l;
        if (__popcll(mask) > 1) {
            unsigned mc = eligible ? myM : 0xFFFFFFFFu;
#pragma unroll
            for (int off = 32; off; off >>= 1) {
                unsigned o = (unsigned)__shfl_xor((int)mc, off, 64);
                mc = o < mc ? o : mc;
            }
            eligible = eligible && (myM == mc);
        }
        if (eligible) {
            idx_out[(size_t)q * 8 + sel] = (int)myM;
            unsigned ws = (unsigned)lm;
#pragma unroll
            for (int g = 0; g < 8; ++g) {
                if (gv[g] == lm) {
                    asm volatile("" ::: "memory");
                    unsigned long long kmin = ~0ULL;
#pragma unroll
                    for (int j = 0; j < 4; ++j) {
                        int i = g * 4 + j;
                        unsigned v = ((unsigned)i == ws) ? 0xFFFFFFFFu : val[i];
                        val[i] = v;
                        unsigned long long kk = ((unsigned long long)v << 32) | (unsigned)i;
                        kmin = kk < kmin ? kk : kmin;
                    }
                    gv[g] = kmin;
                }
            }
            unsigned long long nlm = gv[0];
#pragma unroll
            for (int g = 1; g < 8; ++g) nlm = gv[g] < nlm ? gv[g] : nlm;
            lm = nlm;
        }
    }
}

// ---------------- gather: sums + std partials + ef' (bf16) fused ------------
__global__ __launch_bounds__(128) void gather_kernel(const float* __restrict__ xn,
                                                     const int* __restrict__ idxb,
                                                     const float* __restrict__ alpha,
                                                     unsigned short* __restrict__ efp,
                                                     float2* __restrict__ part) {
    int q = blockIdx.x;
    int b = q >> 11;
    int t = threadIdx.x;
    __shared__ int sidx[8];
    if (t < 8) sidx[t] = idxb[(size_t)q * 8 + t];
    __syncthreads();
    const float* xno = xn + ((size_t)b * 2049 + 1) * C384;
    const float* xc  = xn + ((size_t)q + b + 1) * C384;
    float s1 = 0.f, s2 = 0.f;
    for (int c = t; c < C384; c += 128) {
        float xcv = xc[c];
        float acc = 0.f;
#pragma unroll
        for (int k = 0; k < 8; ++k) {
            float v = xno[(size_t)sidx[k] * C384 + c];
            acc += v;
            float d = v - xcv;
            s1 += d;
            s2 += d * d;
        }
        float mk = acc * 0.125f;
        efp[(size_t)q * 768 + c]       = f2bf(alpha[c] * (mk - xcv));
        efp[(size_t)q * 768 + 384 + c] = f2bf(alpha[384 + c] * xcv);
    }
    __shared__ float r1[128], r2[128];
    r1[t] = s1; r2[t] = s2;
    __syncthreads();
#pragma unroll
    for (int s = 64; s; s >>= 1) {
        if (t < s) { r1[t] += r1[t + s]; r2[t] += r2[t + s]; }
        __syncthreads();
    }
    if (t == 0) part[q] = make_float2(r1[0], r2[0]);
}

// ---------------- bf16 MFMA GEMM, 64x64 tile, BK=64, global_load_lds ---------
// Staging via global_load_lds width=16: LDS dest linear (lane*16), global
// source pre-swizzled (chunk_g = (l&7)^(l>>3); row&7 == l>>3 for every
// 8-row segment, so the read-side XOR addressing is unchanged).
// Schedule: issue DMA(t+1) -> compute(t) -> __syncthreads (loads fly under
// MFMA; barrier drains vmcnt - m97 structure).
#define ST_STR 68

template <bool GELU, bool REMAP, bool RES, bool OUTBF>
__global__ __launch_bounds__(256) void mfma_gemm(const unsigned short* __restrict__ A,
                                                 const unsigned short* __restrict__ Bt,
                                                 const float* __restrict__ bias,
                                                 const float* __restrict__ res,
                                                 void* __restrict__ outp,
                                                 int M, int N, int K, int ntn) {
    __shared__ char smem[32768];   // 2 bufs x (A 8K | B 8K)
    int t = threadIdx.x;
    int lane = t & 63, w = t >> 6;
    int wr = w >> 1, wc = w & 1;

    int nwg = gridDim.x;
    int q8 = nwg >> 3, r8 = nwg & 7;
    int xcd = blockIdx.x & 7, idx = blockIdx.x >> 3;
    int lid = (xcd < r8 ? xcd * (q8 + 1) : r8 * (q8 + 1) + (xcd - r8) * q8) + idx;
    int by = lid / ntn, bx = lid - by * ntn;
    int bm = by * 64, bn = bx * 64;

    f32x4 acc[2][2] = {};

    // DMA staging plan: 16 segments x 1KB (A rows 0..63 = segs 0..7,
    // B rows 0..63 = segs 8..15). Wave w owns segs w*4..w*4+3.
    // Lane l -> row_in_seg = l>>3, lds chunk = l&7, global chunk = (l&7)^(l>>3).
    const unsigned short* gbase[4];
    int lsegoff[4];
#pragma unroll
    for (int i = 0; i < 4; ++i) {
        int s = w * 4 + i;
        int row = (s & 7) * 8 + (lane >> 3);
        int cg = ((lane & 7) ^ (lane >> 3)) * 8;
        if (s < 8) {
            int gm = bm + row;
            if (gm > M - 1) gm = M - 1;          // tail clamp (dest stays valid)
            gbase[i] = A + (size_t)gm * K + cg;
        } else {
            gbase[i] = Bt + (size_t)(bn + row) * K + cg;
        }
        lsegoff[i] = s * 1024;
    }

    auto issue = [&](int tile, int bufoff) {
        int ko = tile << 6;
#pragma unroll
        for (int i = 0; i < 4; ++i)
            __builtin_amdgcn_global_load_lds(
                (const __attribute__((address_space(1))) void*)(gbase[i] + ko),
                (__attribute__((address_space(3))) void*)(smem + bufoff + lsegoff[i]),
                16, 0, 0);
    };
    auto compute = [&](const char* smA) {
        const char* smB = smA + 8192;
#pragma unroll
        for (int ks = 0; ks < 2; ++ks) {
            short8 af[2], bfr[2];
            int cb = ks * 4 + (lane >> 4);
#pragma unroll
            for (int mi = 0; mi < 2; ++mi) {
                int row = wr * 32 + mi * 16 + (lane & 15);
                af[mi] = *(const short8*)(smA + row * 128 + ((cb ^ (row & 7)) << 4));
            }
#pragma unroll
            for (int nj = 0; nj < 2; ++nj) {
                int row = wc * 32 + nj * 16 + (lane & 15);
                bfr[nj] = *(const short8*)(smB + row * 128 + ((cb ^ (row & 7)) << 4));
            }
#pragma unroll
            for (int mi = 0; mi < 2; ++mi)
#pragma unroll
                for (int nj = 0; nj < 2; ++nj)
                    acc[mi][nj] = __builtin_amdgcn_mfma_f32_16x16x32_bf16(
                        af[mi], bfr[nj], acc[mi][nj], 0, 0, 0);
        }
    };

    int nt = K >> 6;
    issue(0, 0);
    __syncthreads();
    for (int tix = 0; tix < nt; ++tix) {
        if (tix + 1 < nt) issue(tix + 1, ((tix + 1) & 1) * 16384);
        compute(smem + (tix & 1) * 16384);
        __syncthreads();
    }

    // ---- epilogue: stage f32 tile in LDS, then coalesced full-line stores ----
    float* st = (float*)smem;
#pragma unroll
    for (int nj = 0; nj < 2; ++nj) {
        int nl = wc * 32 + nj * 16 + (lane & 15);
        float bs = bias[bn + nl];
#pragma unroll
        for (int mi = 0; mi < 2; ++mi) {
#pragma unroll
            for (int r = 0; r < 4; ++r) {
                int ml = wr * 32 + mi * 16 + (lane >> 4) * 4 + r;
                float v = acc[mi][nj][r] + bs;
                if (GELU) v = gelu_exact(v);
                st[ml * ST_STR + nl] = v;
            }
        }
    }
    __syncthreads();
    if (OUTBF) {
#pragma unroll
        for (int i = 0; i < 2; ++i) {
            int chunk = t + i * 256;
            int ml = chunk >> 3, c8 = (chunk & 7) * 8;
            int m = bm + ml;
            if (m < M) {
                unsigned short tmp[8];
#pragma unroll
                for (int j = 0; j < 8; ++j) tmp[j] = f2bf(st[ml * ST_STR + c8 + j]);
                *(uint4*)((unsigned short*)outp + (size_t)m * N + bn + c8) = *(uint4*)tmp;
            }
        }
    } else {
#pragma unroll
        for (int i = 0; i < 4; ++i) {
            int chunk = t + i * 256;
            int ml = chunk >> 4, c4 = (chunk & 15) * 4;
            int m = bm + ml;
            if (m < M) {
                size_t orow = REMAP ? (size_t)(m + (m >> 11) + 1) : (size_t)m;
                size_t off = orow * (size_t)N + bn + c4;
                float4 v = *(float4*)&st[ml * ST_STR + c4];
                if (RES) {
                    float4 rv = *(const float4*)(res + off);
                    v.x += rv.x; v.y += rv.y; v.z += rv.z; v.w += rv.w;
                }
                *(float4*)((float*)outp + off) = v;
            }
        }
    }
}

// ---------------------------------------------------------------------------
extern "C" void kernel_launch(void* const* d_in, const int* in_sizes, int n_in,
                              void* d_out, int out_size, void* d_ws, size_t ws_size,
                              hipStream_t stream) {
    const float* center  = (const float*)d_in[0];
    const float* x       = (const float*)d_in[1];
    const float* ln1_g   = (const float*)d_in[2];
    const float* ln1_b   = (const float*)d_in[3];
    const float* alpha   = (const float*)d_in[4];
    const float* beta    = (const float*)d_in[5];
    const float* attn_w1 = (const float*)d_in[6];
    const float* attn_b1 = (const float*)d_in[7];
    const float* attn_w2 = (const float*)d_in[8];
    const float* attn_b2 = (const float*)d_in[9];
    const float* ln2_g   = (const float*)d_in[10];
    const float* ln2_b   = (const float*)d_in[11];
    const float* mlp_w1  = (const float*)d_in[12];
    const float* mlp_b1  = (const float*)d_in[13];
    const float* mlp_w2  = (const float*)d_in[14];
    const float* mlp_b2  = (const float*)d_in[15];
    float* out = (float*)d_out;

    // workspace layout (bytes; g overlays dead xn/efp region)
    char* wsb = (char*)d_ws;
    float*          xn     = (float*)(wsb + 0);                  // 12,589,056 (ln1->ln2)
    unsigned short* efp    = (unsigned short*)(wsb + 12589056);  // 12,582,912 (gather->gemm1)
    int*            idxb   = (int*)(wsb + 25171968);             // 262,144
    float2*         part   = (float2*)(wsb + 25434112);          // 65,536
    float*          stdbuf = (float*)(wsb + 25499648);           // 256
    float4*         pts4   = (float4*)(wsb + 25499904);          // 131,072
    float*          cv     = (float*)(wsb + 25630976);           // 1,536
    unsigned short* h1     = (unsigned short*)(wsb + 25632512);  // 6,291,456 (gemm1->gemm2)
    unsigned short* yb     = (unsigned short*)(wsb + 31923968);  // 6,294,528 (ln2->gemm3)
    unsigned short* g      = (unsigned short*)(wsb + 0);         // 25,178,112 overlay (gemm3->gemm4)
    unsigned short* w1T    = (unsigned short*)(wsb + 38218496);  // 589,824
    unsigned short* w2T    = (unsigned short*)(wsb + 38808320);  // 294,912
    unsigned short* mw1T   = (unsigned short*)(wsb + 39103232);  // 1,179,648
    unsigned short* mw2T   = (unsigned short*)(wsb + 40282880);  // 1,179,648 -> 41,462,528
    float*          cvpart = (float*)(wsb + 41462528);           // 49,152

    // 0. prep: LN1 + transposes + pts4 + cv partials (one grid)
    prep_kernel<<<3569, 256, 0, stream>>>(x, ln1_g, ln1_b, xn,
                                          attn_w2, mlp_w1, mlp_w2, center, beta,
                                          attn_w1, w2T, mw1T, mw2T, pts4, cvpart);
    // 1. KNN
    knn_kernel<<<2048, 256, 0, stream>>>(pts4, idxb);
    // 2. gather (+fused ef')
    gather_kernel<<<8192, 128, 0, stream>>>(xn, idxb, alpha, efp, part);
    // 3. std (block 0) + cv reduce (block 1)
    std_kernel<<<2, 256, 0, stream>>>(part, stdbuf, cvpart, attn_b1, cv);
    // 4. W1 transpose+cast with inv on top half
    tcastw1_kernel<<<288, 256, 0, stream>>>(attn_w1, stdbuf, w1T);
    // 5. h1 = gelu(ef' @ w1T + cv)       M=8192 N=384 K=768  (128 x 6)
    mfma_gemm<true, false, false, true><<<768, 256, 0, stream>>>(
        efp, w1T, cv, nullptr, h1, 8192, 384, 768, 6);
    // 6. out[remap] = x + h1 @ w2T + b2  M=8192 N=384 K=384
    mfma_gemm<false, true, true, false><<<768, 256, 0, stream>>>(
        h1, w2T, attn_b2, x, out, 8192, 384, 384, 6);
    // 7. LN2 (+cls fusion) -> yb bf16
    ln2_kernel<<<2049, 256, 0, stream>>>(x, xn, out, yb, ln2_g, ln2_b);
    // 8. g = gelu(yb @ mw1T + b1)        M=8196 N=1536 K=384  (129 x 24)
    mfma_gemm<true, false, false, true><<<3096, 256, 0, stream>>>(
        yb, mw1T, mlp_b1, nullptr, g, 8196, 1536, 384, 24);
    // 9. out += g @ mw2T + b2            M=8196 N=384 K=1536  (129 x 6)
    mfma_gemm<false, false, true, false><<<774, 256, 0, stream>>>(
        g, mw2T, mlp_b2, out, out, 8196, 384, 1536, 6);
}